// Round 16
// baseline (207.629 us; speedup 1.0000x reference)
//
#include <hip/hip_runtime.h>
#include <stdint.h>
#include <math.h>

typedef unsigned short u16;
typedef _Float16 f16;
typedef __attribute__((ext_vector_type(4))) float f32x4;
typedef __attribute__((ext_vector_type(8))) f16 h8;
typedef __attribute__((ext_vector_type(4))) f16 h4;
typedef __attribute__((ext_vector_type(2))) f16 h2;
typedef __attribute__((ext_vector_type(2))) __fp16 fp16x2;
typedef __attribute__((ext_vector_type(2))) unsigned int u32x2;
typedef __attribute__((ext_vector_type(4))) unsigned int u32x4;
typedef __attribute__((ext_vector_type(4))) unsigned short u16x4;
typedef __attribute__((ext_vector_type(8))) unsigned short u16x8;

typedef const __attribute__((address_space(1))) u16 gas_u16;
typedef __attribute__((address_space(3))) u16 las_u16;

#define MFMA32(a,b,c) __builtin_amdgcn_mfma_f32_16x16x32_f16((a),(b),(c),0,0,0)
#define MFMA16(a,b,c) __builtin_amdgcn_mfma_f32_16x16x16f16((a),(b),(c),0,0,0)

__device__ __forceinline__ float h2f(u16 h){ f16 x; __builtin_memcpy(&x,&h,2); return (float)x; }
__device__ __forceinline__ u16 f2h(float f){ f16 x = (f16)f; u16 u; __builtin_memcpy(&u,&x,2); return u; }

__device__ __forceinline__ float fast_exp2(float x){
#if __has_builtin(__builtin_amdgcn_exp2f)
  return __builtin_amdgcn_exp2f(x);
#else
  return exp2f(x);
#endif
}

// pack two f32 -> two f16 in one v_cvt_pkrtz; bit-cast to _Float16 vector type
__device__ __forceinline__ h2 pkrtz(float a, float b){
  fp16x2 t = __builtin_amdgcn_cvt_pkrtz(a, b);
  h2 r; __builtin_memcpy(&r, &t, 4);
  return r;
}

// ---------------- fused fp32 -> fp16 convert (x, w1, w2 in one launch) ----------------
#define NA4 1572864
#define NB4 442368
#define NC4 147456
__global__ __launch_bounds__(256) void cvt3_kernel(
    const float* __restrict__ a, u16* __restrict__ da,
    const float* __restrict__ b, u16* __restrict__ db,
    const float* __restrict__ c, u16* __restrict__ dc)
{
  int i = blockIdx.x*256 + threadIdx.x;
  const float* s; u16* d; int off;
  if (i < NA4)            { s = a; d = da; off = i; }
  else if (i < NA4+NB4)   { s = b; d = db; off = i - NA4; }
  else if (i < NA4+NB4+NC4){ s = c; d = dc; off = i - NA4 - NB4; }
  else return;
  f32x4 v = ((const f32x4*)s)[off];
  u16x4 o;
  o[0]=f2h(v[0]); o[1]=f2h(v[1]); o[2]=f2h(v[2]); o[3]=f2h(v[3]);
  ((u16x4*)d)[off] = o;
}

// ---------------- fp16 GEMM, C = A(M x 768) * B(N x 768)^T + bias ----------------
// R15 structure (kept): BM=128 BN=256 BK=64, 512 threads = 8 waves, triple-
// buffered slots, counted vmcnt(6), per-phase barriers + setprio. gemm1 plateaus
// at ~54us across 7 structures (R8-R15) — accepted for this problem shape.
// mode 0: q/k row-normalize (+ logit_scale*log2e on q) scatter + V transpose.
// mode 1: fp32 out (M x 768).
#define GSLOT 24576   // u16 per slot: A 128*64 + B 256*64
__global__ __launch_bounds__(512, 2) void gemm_kernel(
    const u16* __restrict__ A, const u16* __restrict__ B, const float* __restrict__ bias,
    int mode, u16* __restrict__ qh, u16* __restrict__ kh, u16* __restrict__ vtp,
    float* __restrict__ outp, const float* __restrict__ lsb)
{
  __shared__ u16 L[3*GSLOT];      // 144KB
  const int tid = threadIdx.x;
  const int lane = tid & 63;
  const int w = tid >> 6;               // 0..7
  const int wm = w >> 2, wn = w & 3;    // 2M x 4N wave grid
  const int lo = lane & 15, hi = lane >> 4;

  const int bx = blockIdx.x, by = blockIdx.y;

  f32x4 zero = {0.f,0.f,0.f,0.f};
  f32x4 acc[4][4];
#pragma unroll
  for (int a=0;a<4;a++)
#pragma unroll
    for (int b=0;b<4;b++) acc[a][b] = zero;
  const u16* Ag = A + (size_t)bx*128*768;
  const u16* Bg = B + (size_t)by*256*768;
  const int srow = tid >> 3;                         // 0..63
  const int scol = (((tid & 7) ^ (srow & 7)) * 8);   // pre-swizzled source 16B-slot

  // half 0: A rows srow, srow+64 and B rows srow; half 1: B rows srow+64/128/192
#define STG(slot, kt, half) do { \
    if ((half) == 0) { \
      __builtin_amdgcn_global_load_lds((gas_u16*)(Ag + (size_t)srow*768 + (kt) + scol),      (las_u16*)(&L[(slot)*GSLOT + tid*8]),        16, 0, 0); \
      __builtin_amdgcn_global_load_lds((gas_u16*)(Ag + (size_t)(srow+64)*768 + (kt) + scol), (las_u16*)(&L[(slot)*GSLOT + 4096 + tid*8]), 16, 0, 0); \
      __builtin_amdgcn_global_load_lds((gas_u16*)(Bg + (size_t)srow*768 + (kt) + scol),      (las_u16*)(&L[(slot)*GSLOT + 8192 + tid*8]), 16, 0, 0); \
    } else { \
      __builtin_amdgcn_global_load_lds((gas_u16*)(Bg + (size_t)(srow+64)*768 + (kt) + scol),  (las_u16*)(&L[(slot)*GSLOT + 12288 + tid*8]), 16, 0, 0); \
      __builtin_amdgcn_global_load_lds((gas_u16*)(Bg + (size_t)(srow+128)*768 + (kt) + scol), (las_u16*)(&L[(slot)*GSLOT + 16384 + tid*8]), 16, 0, 0); \
      __builtin_amdgcn_global_load_lds((gas_u16*)(Bg + (size_t)(srow+192)*768 + (kt) + scol), (las_u16*)(&L[(slot)*GSLOT + 20480 + tid*8]), 16, 0, 0); \
    } \
  } while(0)

  STG(0, 0, 0);  STG(0, 0, 1);     // tile 0
  STG(1, 64, 0); STG(1, 64, 1);    // tile 1
  asm volatile("s_waitcnt vmcnt(6)" ::: "memory");   // tile 0 landed; tile 1 in flight
  __builtin_amdgcn_sched_barrier(0);
  __builtin_amdgcn_s_barrier();

  int cs = 0;                       // slot holding tile t
  for (int t = 0; t < 12; ++t) {
    const u16* LA = L + cs*GSLOT;
    const u16* LB = LA + 8192;
    int ss = cs + 2; if (ss >= 3) ss -= 3;   // slot for tile t+2
#pragma unroll
    for (int kk = 0; kk < 2; ++kk) {
      const int rsl = ((hi + 4*kk) ^ (lo & 7)) * 8;
      h8 af[4], bfr[4];
#pragma unroll
      for (int mf=0; mf<4; mf++) af[mf]  = *(const h8*)(LA + (wm*64 + mf*16 + lo)*64 + rsl);
#pragma unroll
      for (int nf=0; nf<4; nf++) bfr[nf] = *(const h8*)(LB + (wn*64 + nf*16 + lo)*64 + rsl);
      if (t < 10) STG(ss, (t+2)*64, kk);               // 3 loads per phase
      __builtin_amdgcn_s_barrier();                    // role-diversity barrier
      asm volatile("s_waitcnt lgkmcnt(0)" ::: "memory");
      __builtin_amdgcn_sched_barrier(0);
      __builtin_amdgcn_s_setprio(1);
#pragma unroll
      for (int mf=0; mf<4; mf++)
#pragma unroll
        for (int nf=0; nf<4; nf++)
          acc[mf][nf] = MFMA32(af[mf], bfr[nf], acc[mf][nf]);
      __builtin_amdgcn_s_setprio(0);
      if (kk == 1) {                                   // counted wait, once/step
        if (t < 10)       asm volatile("s_waitcnt vmcnt(6)" ::: "memory");
        else if (t == 10) asm volatile("s_waitcnt vmcnt(0)" ::: "memory");
        __builtin_amdgcn_sched_barrier(0);
      }
      __builtin_amdgcn_s_barrier();
    }
    cs += 1; if (cs >= 3) cs -= 3;
  }
#undef STG

  const int r0 = bx*128 + wm*64;
  const int j0 = by*256 + wn*64;
  if (mode == 0) {
    const int p = (j0 >= 1536) ? 2 : ((j0 >= 768) ? 1 : 0);
    float bi[4];
#pragma unroll
    for (int nf=0;nf<4;nf++) bi[nf] = bias[j0 + nf*16 + lo];
    if (p == 2) {
      // ---- V: transposed store via dead LDS; 4 per-wn tiles T[d(64)][r(128)] ----
      u16* Tt = (u16*)L + wn*8192;
#pragma unroll
      for (int mf=0; mf<4; mf++)
#pragma unroll
        for (int nf=0; nf<4; nf++) {
          int d = nf*16 + lo;
          int c = wm*16 + mf*4 + hi;          // r-chunk (r = c*4 + i), 0..31
          u16x4 pk;
#pragma unroll
          for (int i=0;i<4;i++) pk[i] = f2h(acc[mf][nf][i] + bi[nf]);
          *(u16x4*)(Tt + d*128 + ((c ^ ((d & 7) << 2)) << 2)) = pk;
        }
      __syncthreads();
      // gather 8 l-consecutive elems per task, write 16B to vt
#pragma unroll
      for (int kq=0; kq<8; kq++) {
        int idx = tid + kq*512;               // [tw][lh][d][nn], nn fastest
        int nn  = idx & 7;
        int d   = (idx >> 3) & 63;
        int lh  = (idx >> 9) & 1;
        int tw  = idx >> 10;                  // 0..3
        const u16* Ts = (const u16*)L + tw*8192;
        int hh = (by - 6)*4 + tw;
        u16x8 v8;
#pragma unroll
        for (int ll=0; ll<8; ll++) {
          int rl = (lh*8 + ll)*8 + nn;        // r_local = l_local*8 + n
          int c  = rl >> 2;
          v8[ll] = Ts[d*128 + ((c ^ ((d & 7) << 2)) << 2) + (rl & 3)];
        }
        size_t off = (((size_t)nn*12 + hh)*64 + d)*1024 + (size_t)bx*16 + lh*8;
        *(u16x8*)(vtp + off) = v8;
      }
    } else {
      // ---- q/k: fused row-normalize + scatter ----
      const int c0 = j0 - p*768;
      const int hh = c0 >> 6;
      u16* dst = (p==0) ? qh : kh;
      float qsc = 1.0f;
      if (p == 0) qsc = __expf(fminf(lsb[hh], 4.6051701859880913680f)) * 1.4426950408889634f;
#pragma unroll
      for (int mf=0; mf<4; mf++)
#pragma unroll
        for (int i=0;i<4;i++) {
          int r = r0 + mf*16 + 4*hi + i;
          int n = r & 7, l = r >> 3;
          float v[4]; float ss2 = 0.f;
#pragma unroll
          for (int nf=0;nf<4;nf++){ v[nf] = acc[mf][nf][i] + bi[nf]; ss2 += v[nf]*v[nf]; }
          ss2 += __shfl_xor(ss2, 1);
          ss2 += __shfl_xor(ss2, 2);
          ss2 += __shfl_xor(ss2, 4);
          ss2 += __shfl_xor(ss2, 8);
          float sc = qsc / fmaxf(sqrtf(ss2), 1e-12f);
          size_t base = (((size_t)n*12 + hh)*1024 + l)*64;
#pragma unroll
          for (int nf=0;nf<4;nf++)
            dst[base + nf*16 + lo] = f2h(v[nf]*sc);
        }
    }
  } else {
#pragma unroll
    for (int nf=0; nf<4; nf++) {
      int j = j0 + nf*16 + lo;
      float bi = bias[j];
#pragma unroll
      for (int mf=0; mf<4; mf++)
#pragma unroll
        for (int i=0;i<4;i++) {
          int r = r0 + mf*16 + 4*hi + i;
          outp[(size_t)r*768 + j] = acc[mf][nf][i] + bi;
        }
    }
  }
}

// ---------------- flash attention: LDS-FREE (K/V L2-resident) ----------------
// R16: per-XCD K+V working set = 12 heads x 256KB = 3MB < 4MB L2 -> staging
// through LDS was pure overhead (guide m168->m169). K fragments are read
// DIRECTLY from global: lane addr = base + lo*128 + hi*16 covers a contiguous
// 2KB block per wave (fully coalesced, L2-hit). V^T fragments: 8B/lane over
// 16 rows (64B-line aligned). NO __shared__, NO barriers, NO lgkm waits in the
// loop - 12 independent waves/CU + 24 in-flight loads/iter hide L2 latency.
// 32 q-rows/wave (2 groups a/b) kept: K/V loads serve both accumulator sets.
__global__ __launch_bounds__(256, 3) void flash_kernel(
    const u16* __restrict__ qh, const u16* __restrict__ kh, const u16* __restrict__ vt,
    u16* __restrict__ obuf, const float* __restrict__ hsv, const float* __restrict__ lsp)
{
  // XCD-locality remap: 12 heads x 8 q-tiles per XCD (3MB K+V resident in L2)
  const int lin = blockIdx.y*8 + blockIdx.x;
  const int xcd = lin & 7, g = lin >> 3;
  const int nh = xcd + 8*(g >> 3);
  const int qt = g & 7;
  const int h = nh % 12, n = nh / 12;
  const u16* Qp = qh + (size_t)nh*65536;
  const u16* Kp = kh + (size_t)nh*65536;
  const u16* Vp = vt + (size_t)nh*65536;
  const int tid = threadIdx.x, lane = tid & 63, w = tid >> 6;
  const int lo = lane & 15, hi = lane >> 4;

  // Q fragments, both q-groups: lane holds Q[q=lo(+16)][d = hi*8 + j] (+32)
  h8 qa0, qa1, qb0, qb1;
  {
    const u16* qrow = Qp + (size_t)(qt*128 + w*32 + lo)*64 + hi*8;
    qa0 = *(const h8*)qrow;          qa1 = *(const h8*)(qrow + 32);
    qb0 = *(const h8*)(qrow + 1024); qb1 = *(const h8*)(qrow + 1024 + 32);
  }
  const f32x4 zero = {0.f,0.f,0.f,0.f};
  f32x4 oA[4] = {zero,zero,zero,zero};   // O^T[d=db*16+4hi+i][q=lo]
  f32x4 oB[4] = {zero,zero,zero,zero};
  f32x4 lA4 = zero, lB4 = zero;          // row sums via ones-MFMA
  const h4 ones = {(f16)1.f,(f16)1.f,(f16)1.f,(f16)1.f};

  // fp16-overflow guard (0 for these inputs; uniform branch if ever nonzero)
  float OFF;
  {
    float b = __expf(fminf(lsp[h], 4.6051701859880913680f)) * 1.4426950408889634f;
    OFF = fmaxf(b - 15.5f, 0.f);
  }

  // per-lane fragment base addresses
  const u16* kbase = Kp + (size_t)lo*64 + hi*8;            // + t*4096 + kf*1024 (+32)
  const u16* vbase = Vp + (size_t)lo*1024 + hi*4;          // + db*16384 + t*64 + kf*16

  for (int t = 0; t < 16; ++t) {
    // ---- K fragments: direct, coalesced (2KB contiguous per wave per kf) ----
    h8 k0[4], k1[4];
#pragma unroll
    for (int kf=0; kf<4; kf++) {
      const u16* kr = kbase + (size_t)t*4096 + (size_t)kf*1024;
      k0[kf] = *(const h8*)kr;
      k1[kf] = *(const h8*)(kr + 32);
    }
    // ---- V fragments: direct 8B loads (issued early; wait under PV) ----
    h4 vf[4][4];
#pragma unroll
    for (int db=0; db<4; db++)
#pragma unroll
      for (int kf=0; kf<4; kf++)
        vf[db][kf] = *(const h4*)(vbase + (size_t)db*16384 + t*64 + kf*16);
    // ---- S^T = K . Q^T, both q-groups ----
    f32x4 sa[4], sb[4];
#pragma unroll
    for (int kf=0; kf<4; kf++) {
      sa[kf] = MFMA32(k1[kf], qa1, MFMA32(k0[kf], qa0, zero));
      sb[kf] = MFMA32(k1[kf], qb1, MFMA32(k0[kf], qb0, zero));
    }
    if (OFF != 0.f) {
#pragma unroll
      for (int kf=0;kf<4;kf++)
#pragma unroll
        for (int i=0;i<4;i++) { sa[kf][i] -= OFF; sb[kf][i] -= OFF; }
    }
    // ---- p = exp2(s), packed into mfma16 B-operand layout ----
    h4 pa[4], pb[4];
#pragma unroll
    for (int kf=0;kf<4;kf++) {
      h2 a01 = pkrtz(fast_exp2(sa[kf][0]), fast_exp2(sa[kf][1]));
      h2 a23 = pkrtz(fast_exp2(sa[kf][2]), fast_exp2(sa[kf][3]));
      pa[kf] = __builtin_shufflevector(a01, a23, 0, 1, 2, 3);
      h2 b01 = pkrtz(fast_exp2(sb[kf][0]), fast_exp2(sb[kf][1]));
      h2 b23 = pkrtz(fast_exp2(sb[kf][2]), fast_exp2(sb[kf][3]));
      pb[kf] = __builtin_shufflevector(b01, b23, 0, 1, 2, 3);
    }
    // ---- row sums on the matrix pipe ----
#pragma unroll
    for (int kf=0;kf<4;kf++) {
      lA4 = MFMA16(ones, pa[kf], lA4);
      lB4 = MFMA16(ones, pb[kf], lB4);
    }
    // ---- PV: O^T += VT-frag x P-frag ----
#pragma unroll
    for (int db=0; db<4; db++) {
#pragma unroll
      for (int kf=0; kf<4; kf++) {
        oA[db] = MFMA16(vf[db][kf], pa[kf], oA[db]);
        oB[db] = MFMA16(vf[db][kf], pb[kf], oB[db]);
      }
    }
  }
  // epilogue: O[q][d] = O^T / l * head_scale, store fp16 into (L,N,C)
  float hsc = hsv[h];
  float invA = hsc / lA4[0];
  float invB = hsc / lB4[0];
  int l0 = qt*128 + w*32 + lo;
  u16* dA = obuf + ((size_t)l0*8 + n)*768 + h*64;
  u16* dB = obuf + ((size_t)(l0+16)*8 + n)*768 + h*64;
#pragma unroll
  for (int db=0; db<4; db++) {
    u16x4 pk0, pk1;
#pragma unroll
    for (int i=0;i<4;i++) { pk0[i] = f2h(oA[db][i]*invA); pk1[i] = f2h(oB[db][i]*invB); }
    *(u16x4*)(dA + db*16 + hi*4) = pk0;
    *(u16x4*)(dB + db*16 + hi*4) = pk1;
  }
}

extern "C" void kernel_launch(void* const* d_in, const int* in_sizes, int n_in,
                              void* d_out, int out_size, void* d_ws, size_t ws_size,
                              hipStream_t stream)
{
  (void)in_sizes; (void)n_in; (void)out_size; (void)ws_size;
  const float* x  = (const float*)d_in[0];
  const float* w1 = (const float*)d_in[1];
  const float* b1 = (const float*)d_in[2];
  const float* ls = (const float*)d_in[3];
  const float* hs = (const float*)d_in[4];
  const float* w2 = (const float*)d_in[5];
  const float* b2 = (const float*)d_in[6];
  float* out = (float*)d_out;

  u16* x_bf  = (u16*)d_ws;            // 8192 x 768  (reused as ob after GEMM1)
  u16* w1_bf = x_bf  + 6291456;       // 2304 x 768
  u16* w2_bf = w1_bf + 1769472;       // 768 x 768
  u16* qh    = w2_bf + 589824;        // (N,H,L,D) normalized (+ls*log2e on q)
  u16* kh    = qh    + 6291456;
  u16* vt    = kh    + 6291456;       // (N,H,D,L) — written directly by gemm1
  u16* ob    = x_bf;                  // (L,N,C) fp16, aliases x_bf

  cvt3_kernel<<<8448, 256, 0, stream>>>(x, x_bf, w1, w1_bf, w2, w2_bf);
  gemm_kernel<<<dim3(64,9), 512, 0, stream>>>(x_bf, w1_bf, b1, 0, qh, kh, vt, nullptr, ls);
  flash_kernel<<<dim3(8,96), 256, 0, stream>>>(qh, kh, vt, ob, hs, ls);
  gemm_kernel<<<dim3(64,3), 512, 0, stream>>>(ob, w2_bf, b2, 1, nullptr, nullptr, nullptr, out, ls);
}

// Round 17
// 114.468 us; speedup vs baseline: 1.8139x; 1.8139x over previous
//
#include <hip/hip_runtime.h>
#include <stdint.h>
#include <math.h>

typedef unsigned short u16;
typedef _Float16 f16;
typedef __attribute__((ext_vector_type(4))) float f32x4;
typedef __attribute__((ext_vector_type(8))) f16 h8;
typedef __attribute__((ext_vector_type(4))) f16 h4;
typedef __attribute__((ext_vector_type(2))) f16 h2;
typedef __attribute__((ext_vector_type(2))) __fp16 fp16x2;
typedef __attribute__((ext_vector_type(2))) unsigned int u32x2;
typedef __attribute__((ext_vector_type(4))) unsigned int u32x4;
typedef __attribute__((ext_vector_type(4))) unsigned short u16x4;
typedef __attribute__((ext_vector_type(8))) unsigned short u16x8;

typedef const __attribute__((address_space(1))) u16 gas_u16;
typedef __attribute__((address_space(3))) u16 las_u16;

#define MFMA32(a,b,c) __builtin_amdgcn_mfma_f32_16x16x32_f16((a),(b),(c),0,0,0)
#define MFMA16(a,b,c) __builtin_amdgcn_mfma_f32_16x16x16f16((a),(b),(c),0,0,0)

__device__ __forceinline__ float h2f(u16 h){ f16 x; __builtin_memcpy(&x,&h,2); return (float)x; }
__device__ __forceinline__ u16 f2h(float f){ f16 x = (f16)f; u16 u; __builtin_memcpy(&u,&x,2); return u; }

__device__ __forceinline__ float fast_exp2(float x){
#if __has_builtin(__builtin_amdgcn_exp2f)
  return __builtin_amdgcn_exp2f(x);
#else
  return exp2f(x);
#endif
}

// pack two f32 -> two f16 in one v_cvt_pkrtz; bit-cast to _Float16 vector type
__device__ __forceinline__ h2 pkrtz(float a, float b){
  fp16x2 t = __builtin_amdgcn_cvt_pkrtz(a, b);
  h2 r; __builtin_memcpy(&r, &t, 4);
  return r;
}

// ---------------- fused fp32 -> fp16 convert (x, w1, w2 in one launch) ----------------
#define NA4 1572864
#define NB4 442368
#define NC4 147456
__global__ __launch_bounds__(256) void cvt3_kernel(
    const float* __restrict__ a, u16* __restrict__ da,
    const float* __restrict__ b, u16* __restrict__ db,
    const float* __restrict__ c, u16* __restrict__ dc)
{
  int i = blockIdx.x*256 + threadIdx.x;
  const float* s; u16* d; int off;
  if (i < NA4)            { s = a; d = da; off = i; }
  else if (i < NA4+NB4)   { s = b; d = db; off = i - NA4; }
  else if (i < NA4+NB4+NC4){ s = c; d = dc; off = i - NA4 - NB4; }
  else return;
  f32x4 v = ((const f32x4*)s)[off];
  u16x4 o;
  o[0]=f2h(v[0]); o[1]=f2h(v[1]); o[2]=f2h(v[2]); o[3]=f2h(v[3]);
  ((u16x4*)d)[off] = o;
}

// ---------------- fp16 GEMM, C = A(M x 768) * B(N x 768)^T + bias ----------------
// R15 structure (kept): BM=128 BN=256 BK=64, 512 threads = 8 waves, triple-
// buffered slots, counted vmcnt(6), per-phase barriers + setprio. gemm1 plateaus
// at ~54us across 7 structures (R8-R15) — accepted for this problem shape.
// mode 0: q/k row-normalize (+ logit_scale*log2e on q) scatter + V transpose.
// mode 1: fp32 out (M x 768).
#define GSLOT 24576   // u16 per slot: A 128*64 + B 256*64
__global__ __launch_bounds__(512, 2) void gemm_kernel(
    const u16* __restrict__ A, const u16* __restrict__ B, const float* __restrict__ bias,
    int mode, u16* __restrict__ qh, u16* __restrict__ kh, u16* __restrict__ vtp,
    float* __restrict__ outp, const float* __restrict__ lsb)
{
  __shared__ u16 L[3*GSLOT];      // 144KB
  const int tid = threadIdx.x;
  const int lane = tid & 63;
  const int w = tid >> 6;               // 0..7
  const int wm = w >> 2, wn = w & 3;    // 2M x 4N wave grid
  const int lo = lane & 15, hi = lane >> 4;

  const int bx = blockIdx.x, by = blockIdx.y;

  f32x4 zero = {0.f,0.f,0.f,0.f};
  f32x4 acc[4][4];
#pragma unroll
  for (int a=0;a<4;a++)
#pragma unroll
    for (int b=0;b<4;b++) acc[a][b] = zero;
  const u16* Ag = A + (size_t)bx*128*768;
  const u16* Bg = B + (size_t)by*256*768;
  const int srow = tid >> 3;                         // 0..63
  const int scol = (((tid & 7) ^ (srow & 7)) * 8);   // pre-swizzled source 16B-slot

  // half 0: A rows srow, srow+64 and B rows srow; half 1: B rows srow+64/128/192
#define STG(slot, kt, half) do { \
    if ((half) == 0) { \
      __builtin_amdgcn_global_load_lds((gas_u16*)(Ag + (size_t)srow*768 + (kt) + scol),      (las_u16*)(&L[(slot)*GSLOT + tid*8]),        16, 0, 0); \
      __builtin_amdgcn_global_load_lds((gas_u16*)(Ag + (size_t)(srow+64)*768 + (kt) + scol), (las_u16*)(&L[(slot)*GSLOT + 4096 + tid*8]), 16, 0, 0); \
      __builtin_amdgcn_global_load_lds((gas_u16*)(Bg + (size_t)srow*768 + (kt) + scol),      (las_u16*)(&L[(slot)*GSLOT + 8192 + tid*8]), 16, 0, 0); \
    } else { \
      __builtin_amdgcn_global_load_lds((gas_u16*)(Bg + (size_t)(srow+64)*768 + (kt) + scol),  (las_u16*)(&L[(slot)*GSLOT + 12288 + tid*8]), 16, 0, 0); \
      __builtin_amdgcn_global_load_lds((gas_u16*)(Bg + (size_t)(srow+128)*768 + (kt) + scol), (las_u16*)(&L[(slot)*GSLOT + 16384 + tid*8]), 16, 0, 0); \
      __builtin_amdgcn_global_load_lds((gas_u16*)(Bg + (size_t)(srow+192)*768 + (kt) + scol), (las_u16*)(&L[(slot)*GSLOT + 20480 + tid*8]), 16, 0, 0); \
    } \
  } while(0)

  STG(0, 0, 0);  STG(0, 0, 1);     // tile 0
  STG(1, 64, 0); STG(1, 64, 1);    // tile 1
  asm volatile("s_waitcnt vmcnt(6)" ::: "memory");   // tile 0 landed; tile 1 in flight
  __builtin_amdgcn_sched_barrier(0);
  __builtin_amdgcn_s_barrier();

  int cs = 0;                       // slot holding tile t
  for (int t = 0; t < 12; ++t) {
    const u16* LA = L + cs*GSLOT;
    const u16* LB = LA + 8192;
    int ss = cs + 2; if (ss >= 3) ss -= 3;   // slot for tile t+2
#pragma unroll
    for (int kk = 0; kk < 2; ++kk) {
      const int rsl = ((hi + 4*kk) ^ (lo & 7)) * 8;
      h8 af[4], bfr[4];
#pragma unroll
      for (int mf=0; mf<4; mf++) af[mf]  = *(const h8*)(LA + (wm*64 + mf*16 + lo)*64 + rsl);
#pragma unroll
      for (int nf=0; nf<4; nf++) bfr[nf] = *(const h8*)(LB + (wn*64 + nf*16 + lo)*64 + rsl);
      if (t < 10) STG(ss, (t+2)*64, kk);               // 3 loads per phase
      __builtin_amdgcn_s_barrier();                    // role-diversity barrier
      asm volatile("s_waitcnt lgkmcnt(0)" ::: "memory");
      __builtin_amdgcn_sched_barrier(0);
      __builtin_amdgcn_s_setprio(1);
#pragma unroll
      for (int mf=0; mf<4; mf++)
#pragma unroll
        for (int nf=0; nf<4; nf++)
          acc[mf][nf] = MFMA32(af[mf], bfr[nf], acc[mf][nf]);
      __builtin_amdgcn_s_setprio(0);
      if (kk == 1) {                                   // counted wait, once/step
        if (t < 10)       asm volatile("s_waitcnt vmcnt(6)" ::: "memory");
        else if (t == 10) asm volatile("s_waitcnt vmcnt(0)" ::: "memory");
        __builtin_amdgcn_sched_barrier(0);
      }
      __builtin_amdgcn_s_barrier();
    }
    cs += 1; if (cs >= 3) cs -= 3;
  }
#undef STG

  const int r0 = bx*128 + wm*64;
  const int j0 = by*256 + wn*64;
  if (mode == 0) {
    const int p = (j0 >= 1536) ? 2 : ((j0 >= 768) ? 1 : 0);
    float bi[4];
#pragma unroll
    for (int nf=0;nf<4;nf++) bi[nf] = bias[j0 + nf*16 + lo];
    if (p == 2) {
      // ---- V: transposed store via dead LDS; 4 per-wn tiles T[d(64)][r(128)] ----
      u16* Tt = (u16*)L + wn*8192;
#pragma unroll
      for (int mf=0; mf<4; mf++)
#pragma unroll
        for (int nf=0; nf<4; nf++) {
          int d = nf*16 + lo;
          int c = wm*16 + mf*4 + hi;          // r-chunk (r = c*4 + i), 0..31
          u16x4 pk;
#pragma unroll
          for (int i=0;i<4;i++) pk[i] = f2h(acc[mf][nf][i] + bi[nf]);
          *(u16x4*)(Tt + d*128 + ((c ^ ((d & 7) << 2)) << 2)) = pk;
        }
      __syncthreads();
      // gather 8 l-consecutive elems per task, write 16B to vt
#pragma unroll
      for (int kq=0; kq<8; kq++) {
        int idx = tid + kq*512;               // [tw][lh][d][nn], nn fastest
        int nn  = idx & 7;
        int d   = (idx >> 3) & 63;
        int lh  = (idx >> 9) & 1;
        int tw  = idx >> 10;                  // 0..3
        const u16* Ts = (const u16*)L + tw*8192;
        int hh = (by - 6)*4 + tw;
        u16x8 v8;
#pragma unroll
        for (int ll=0; ll<8; ll++) {
          int rl = (lh*8 + ll)*8 + nn;        // r_local = l_local*8 + n
          int c  = rl >> 2;
          v8[ll] = Ts[d*128 + ((c ^ ((d & 7) << 2)) << 2) + (rl & 3)];
        }
        size_t off = (((size_t)nn*12 + hh)*64 + d)*1024 + (size_t)bx*16 + lh*8;
        *(u16x8*)(vtp + off) = v8;
      }
    } else {
      // ---- q/k: fused row-normalize + scatter ----
      const int c0 = j0 - p*768;
      const int hh = c0 >> 6;
      u16* dst = (p==0) ? qh : kh;
      float qsc = 1.0f;
      if (p == 0) qsc = __expf(fminf(lsb[hh], 4.6051701859880913680f)) * 1.4426950408889634f;
#pragma unroll
      for (int mf=0; mf<4; mf++)
#pragma unroll
        for (int i=0;i<4;i++) {
          int r = r0 + mf*16 + 4*hi + i;
          int n = r & 7, l = r >> 3;
          float v[4]; float ss2 = 0.f;
#pragma unroll
          for (int nf=0;nf<4;nf++){ v[nf] = acc[mf][nf][i] + bi[nf]; ss2 += v[nf]*v[nf]; }
          ss2 += __shfl_xor(ss2, 1);
          ss2 += __shfl_xor(ss2, 2);
          ss2 += __shfl_xor(ss2, 4);
          ss2 += __shfl_xor(ss2, 8);
          float sc = qsc / fmaxf(sqrtf(ss2), 1e-12f);
          size_t base = (((size_t)n*12 + hh)*1024 + l)*64;
#pragma unroll
          for (int nf=0;nf<4;nf++)
            dst[base + nf*16 + lo] = f2h(v[nf]*sc);
        }
    }
  } else {
#pragma unroll
    for (int nf=0; nf<4; nf++) {
      int j = j0 + nf*16 + lo;
      float bi = bias[j];
#pragma unroll
      for (int mf=0; mf<4; mf++)
#pragma unroll
        for (int i=0;i<4;i++) {
          int r = r0 + mf*16 + 4*hi + i;
          outp[(size_t)r*768 + j] = acc[mf][nf][i] + bi;
        }
    }
  }
}

// ---------------- flash attention (cosine-bounded: no running max needed) ----------------
// R13 structure (32 q-rows/wave, shared K/V frags) + R14 double-buffered K/VT
// tiles -> ONE lgkm+barrier per iteration. (R16's LDS-free variant regressed 4x:
// the V^T gather is 64B-line-granular -> 256 L2 requests/wave/iter; LDS staging
// converts it into one coalesced stream. Reverted.)
__global__ __launch_bounds__(256, 3) void flash_kernel(
    const u16* __restrict__ qh, const u16* __restrict__ kh, const u16* __restrict__ vt,
    u16* __restrict__ obuf, const float* __restrict__ hsv, const float* __restrict__ lsp)
{
  __shared__ u16 lK[2][64*64];    // [buf][k][d] swizzled 16B slots
  __shared__ u16 lVT[2][64*64];   // [buf][d][k] permuted+swizzled 8B chunks
  // XCD-locality remap: 12 heads x 8 q-tiles per XCD (3MB K+V resident in L2)
  const int lin = blockIdx.y*8 + blockIdx.x;
  const int xcd = lin & 7, g = lin >> 3;
  const int nh = xcd + 8*(g >> 3);
  const int qt = g & 7;
  const int h = nh % 12, n = nh / 12;
  const u16* Qp = qh + (size_t)nh*65536;
  const u16* Kp = kh + (size_t)nh*65536;
  const u16* Vp = vt + (size_t)nh*65536;
  const int tid = threadIdx.x, lane = tid & 63, w = tid >> 6;
  const int lo = lane & 15, hi = lane >> 4;
  const int e = lo & 7;

  // Q fragments, both q-groups: lane holds Q[q=lo(+16)][d = hi*8 + j] (+32)
  h8 qa0, qa1, qb0, qb1;
  {
    const u16* qrow = Qp + (size_t)(qt*128 + w*32 + lo)*64 + hi*8;
    qa0 = *(const h8*)qrow;          qa1 = *(const h8*)(qrow + 32);
    qb0 = *(const h8*)(qrow + 1024); qb1 = *(const h8*)(qrow + 1024 + 32);
  }
  const f32x4 zero = {0.f,0.f,0.f,0.f};
  f32x4 oA[4] = {zero,zero,zero,zero};   // O^T[d=db*16+4hi+i][q=lo]
  f32x4 oB[4] = {zero,zero,zero,zero};
  f32x4 lA4 = zero, lB4 = zero;          // row sums via ones-MFMA
  const h4 ones = {(f16)1.f,(f16)1.f,(f16)1.f,(f16)1.f};

  // fp16-overflow guard (0 for these inputs; uniform branch if ever nonzero)
  float OFF;
  {
    float b = __expf(fminf(lsp[h], 4.6051701859880913680f)) * 1.4426950408889634f;
    OFF = fmaxf(b - 15.5f, 0.f);
  }

  const int sr = tid >> 2;          // stage row (k for lK, d for lVT), 0..63
  const int c4 = tid & 3;           // stage 16B-column group
  const int sx1 = sr & 7;           // K slot16 XOR
  const int sx2 = (sr & 7) << 1;    // VT chunk8 XOR (even)

  u32x4 ka, kb, va, vb;
  ka = *(const u32x4*)(Kp + (size_t)sr*64 + c4*16);
  kb = *(const u32x4*)(Kp + (size_t)sr*64 + c4*16 + 8);
  va = *(const u32x4*)(Vp + (size_t)sr*1024 + c4*16);
  vb = *(const u32x4*)(Vp + (size_t)sr*1024 + c4*16 + 8);

#define STAGE_WRITE(bf) do { \
    u16* kr = lK[bf] + sr*64; \
    *(u32x4*)(kr + (((2*c4)   ^ sx1) << 3)) = ka; \
    *(u32x4*)(kr + (((2*c4+1) ^ sx1) << 3)) = kb; \
    u16* vr = lVT[bf] + sr*64; \
    *(u32x2*)(vr + (((( 0|c4) ^ sx2) << 2))) = (u32x2){va[0], va[1]}; \
    *(u32x2*)(vr + (((( 4|c4) ^ sx2) << 2))) = (u32x2){va[2], va[3]}; \
    *(u32x2*)(vr + (((( 8|c4) ^ sx2) << 2))) = (u32x2){vb[0], vb[1]}; \
    *(u32x2*)(vr + ((((12|c4) ^ sx2) << 2))) = (u32x2){vb[2], vb[3]}; \
  } while(0)

  STAGE_WRITE(0);
  asm volatile("s_waitcnt lgkmcnt(0)" ::: "memory");
  __builtin_amdgcn_sched_barrier(0);
  __builtin_amdgcn_s_barrier();

  for (int t = 0; t < 16; ++t) {
    const int cb = t & 1;
    if (t < 15) {  // prefetch next tile into regs; lands under this iter's compute
      ka = *(const u32x4*)(Kp + (size_t)(t+1)*4096 + (size_t)sr*64 + c4*16);
      kb = *(const u32x4*)(Kp + (size_t)(t+1)*4096 + (size_t)sr*64 + c4*16 + 8);
      va = *(const u32x4*)(Vp + (size_t)sr*1024 + (t+1)*64 + c4*16);
      vb = *(const u32x4*)(Vp + (size_t)sr*1024 + (t+1)*64 + c4*16 + 8);
    }
    // ---- S^T = K . Q^T, both q-groups (K fragments read ONCE, used twice) ----
    f32x4 sa[4], sb[4];
#pragma unroll
    for (int kf=0; kf<4; kf++) {
      const u16* krow = lK[cb] + (kf*16 + lo)*64;
      h8 k0 = *(const h8*)(krow + (((hi  ) ^ e) << 3));
      h8 k1 = *(const h8*)(krow + (((hi+4) ^ e) << 3));
      sa[kf] = MFMA32(k1, qa1, MFMA32(k0, qa0, zero));
      sb[kf] = MFMA32(k1, qb1, MFMA32(k0, qb0, zero));
    }
    if (OFF != 0.f) {
#pragma unroll
      for (int kf=0;kf<4;kf++)
#pragma unroll
        for (int i=0;i<4;i++) { sa[kf][i] -= OFF; sb[kf][i] -= OFF; }
    }
    // ---- p = exp2(s), packed into mfma16 B-operand layout ----
    h4 pa[4], pb[4];
#pragma unroll
    for (int kf=0;kf<4;kf++) {
      h2 a01 = pkrtz(fast_exp2(sa[kf][0]), fast_exp2(sa[kf][1]));
      h2 a23 = pkrtz(fast_exp2(sa[kf][2]), fast_exp2(sa[kf][3]));
      pa[kf] = __builtin_shufflevector(a01, a23, 0, 1, 2, 3);
      h2 b01 = pkrtz(fast_exp2(sb[kf][0]), fast_exp2(sb[kf][1]));
      h2 b23 = pkrtz(fast_exp2(sb[kf][2]), fast_exp2(sb[kf][3]));
      pb[kf] = __builtin_shufflevector(b01, b23, 0, 1, 2, 3);
    }
    // ---- row sums on the matrix pipe ----
#pragma unroll
    for (int kf=0;kf<4;kf++) {
      lA4 = MFMA16(ones, pa[kf], lA4);
      lB4 = MFMA16(ones, pb[kf], lB4);
    }
    // ---- PV: O^T += VT-frag x P-frag (V fragments read ONCE, used twice) ----
#pragma unroll
    for (int db=0; db<4; db++) {
      const u16* vrow = lVT[cb] + (db*16 + lo)*64;
      h8 v01 = *(const h8*)(vrow + ((((2*hi  ) ^ e) << 3)));
      h8 v23 = *(const h8*)(vrow + ((((2*hi+1) ^ e) << 3)));
      h4 f0 = __builtin_shufflevector(v01, v01, 0,1,2,3);
      h4 f1 = __builtin_shufflevector(v01, v01, 4,5,6,7);
      h4 f2 = __builtin_shufflevector(v23, v23, 0,1,2,3);
      h4 f3 = __builtin_shufflevector(v23, v23, 4,5,6,7);
      oA[db] = MFMA16(f0, pa[0], oA[db]);
      oB[db] = MFMA16(f0, pb[0], oB[db]);
      oA[db] = MFMA16(f1, pa[1], oA[db]);
      oB[db] = MFMA16(f1, pb[1], oB[db]);
      oA[db] = MFMA16(f2, pa[2], oA[db]);
      oB[db] = MFMA16(f2, pb[2], oB[db]);
      oA[db] = MFMA16(f3, pa[3], oA[db]);
      oB[db] = MFMA16(f3, pb[3], oB[db]);
    }
    // ---- write next tile into the OTHER buffer; single barrier per iter ----
    if (t < 15) STAGE_WRITE(cb ^ 1);
    asm volatile("s_waitcnt lgkmcnt(0)" ::: "memory"); // my ds_writes visible
    __builtin_amdgcn_sched_barrier(0);
    __builtin_amdgcn_s_barrier();
  }
#undef STAGE_WRITE
  // epilogue: O[q][d] = O^T / l * head_scale, store fp16 into (L,N,C)
  float hsc = hsv[h];
  float invA = hsc / lA4[0];
  float invB = hsc / lB4[0];
  int l0 = qt*128 + w*32 + lo;
  u16* dA = obuf + ((size_t)l0*8 + n)*768 + h*64;
  u16* dB = obuf + ((size_t)(l0+16)*8 + n)*768 + h*64;
#pragma unroll
  for (int db=0; db<4; db++) {
    u16x4 pk0, pk1;
#pragma unroll
    for (int i=0;i<4;i++) { pk0[i] = f2h(oA[db][i]*invA); pk1[i] = f2h(oB[db][i]*invB); }
    *(u16x4*)(dA + db*16 + hi*4) = pk0;
    *(u16x4*)(dB + db*16 + hi*4) = pk1;
  }
}

extern "C" void kernel_launch(void* const* d_in, const int* in_sizes, int n_in,
                              void* d_out, int out_size, void* d_ws, size_t ws_size,
                              hipStream_t stream)
{
  (void)in_sizes; (void)n_in; (void)out_size; (void)ws_size;
  const float* x  = (const float*)d_in[0];
  const float* w1 = (const float*)d_in[1];
  const float* b1 = (const float*)d_in[2];
  const float* ls = (const float*)d_in[3];
  const float* hs = (const float*)d_in[4];
  const float* w2 = (const float*)d_in[5];
  const float* b2 = (const float*)d_in[6];
  float* out = (float*)d_out;

  u16* x_bf  = (u16*)d_ws;            // 8192 x 768  (reused as ob after GEMM1)
  u16* w1_bf = x_bf  + 6291456;       // 2304 x 768
  u16* w2_bf = w1_bf + 1769472;       // 768 x 768
  u16* qh    = w2_bf + 589824;        // (N,H,L,D) normalized (+ls*log2e on q)
  u16* kh    = qh    + 6291456;
  u16* vt    = kh    + 6291456;       // (N,H,D,L) — written directly by gemm1
  u16* ob    = x_bf;                  // (L,N,C) fp16, aliases x_bf

  cvt3_kernel<<<8448, 256, 0, stream>>>(x, x_bf, w1, w1_bf, w2, w2_bf);
  gemm_kernel<<<dim3(64,9), 512, 0, stream>>>(x_bf, w1_bf, b1, 0, qh, kh, vt, nullptr, ls);
  flash_kernel<<<dim3(8,96), 256, 0, stream>>>(qh, kh, vt, ob, hs, ls);
  gemm_kernel<<<dim3(64,3), 512, 0, stream>>>(ob, w2_bf, b2, 1, nullptr, nullptr, nullptr, out, ls);
}

// Round 18
// 114.352 us; speedup vs baseline: 1.8157x; 1.0010x over previous
//
#include <hip/hip_runtime.h>
#include <stdint.h>
#include <math.h>

typedef unsigned short u16;
typedef _Float16 f16;
typedef __attribute__((ext_vector_type(4))) float f32x4;
typedef __attribute__((ext_vector_type(8))) f16 h8;
typedef __attribute__((ext_vector_type(4))) f16 h4;
typedef __attribute__((ext_vector_type(2))) f16 h2;
typedef __attribute__((ext_vector_type(2))) __fp16 fp16x2;
typedef __attribute__((ext_vector_type(2))) unsigned int u32x2;
typedef __attribute__((ext_vector_type(4))) unsigned int u32x4;
typedef __attribute__((ext_vector_type(4))) unsigned short u16x4;
typedef __attribute__((ext_vector_type(8))) unsigned short u16x8;

typedef const __attribute__((address_space(1))) u16 gas_u16;
typedef __attribute__((address_space(3))) u16 las_u16;

#define MFMA32(a,b,c) __builtin_amdgcn_mfma_f32_16x16x32_f16((a),(b),(c),0,0,0)
#define MFMA16(a,b,c) __builtin_amdgcn_mfma_f32_16x16x16f16((a),(b),(c),0,0,0)

__device__ __forceinline__ float h2f(u16 h){ f16 x; __builtin_memcpy(&x,&h,2); return (float)x; }
__device__ __forceinline__ u16 f2h(float f){ f16 x = (f16)f; u16 u; __builtin_memcpy(&u,&x,2); return u; }

__device__ __forceinline__ float fast_exp2(float x){
#if __has_builtin(__builtin_amdgcn_exp2f)
  return __builtin_amdgcn_exp2f(x);
#else
  return exp2f(x);
#endif
}

// pack two f32 -> two f16 in one v_cvt_pkrtz; bit-cast to _Float16 vector type
__device__ __forceinline__ h2 pkrtz(float a, float b){
  fp16x2 t = __builtin_amdgcn_cvt_pkrtz(a, b);
  h2 r; __builtin_memcpy(&r, &t, 4);
  return r;
}

// ---------------- fused fp32 -> fp16 convert (x, w1, w2 in one launch) ----------------
#define NA4 1572864
#define NB4 442368
#define NC4 147456
__global__ __launch_bounds__(256) void cvt3_kernel(
    const float* __restrict__ a, u16* __restrict__ da,
    const float* __restrict__ b, u16* __restrict__ db,
    const float* __restrict__ c, u16* __restrict__ dc)
{
  int i = blockIdx.x*256 + threadIdx.x;
  const float* s; u16* d; int off;
  if (i < NA4)            { s = a; d = da; off = i; }
  else if (i < NA4+NB4)   { s = b; d = db; off = i - NA4; }
  else if (i < NA4+NB4+NC4){ s = c; d = dc; off = i - NA4 - NB4; }
  else return;
  f32x4 v = ((const f32x4*)s)[off];
  u16x4 o;
  o[0]=f2h(v[0]); o[1]=f2h(v[1]); o[2]=f2h(v[2]); o[3]=f2h(v[3]);
  ((u16x4*)d)[off] = o;
}

// ---------------- fp16 GEMM, C = A(M x 768) * B(N x 768)^T + bias ----------------
// R15 structure (kept): BM=128 BN=256 BK=64, 512 threads = 8 waves, triple-
// buffered slots, counted vmcnt(6), per-phase barriers + setprio. gemm1 plateaus
// at ~54us across 7 structures (R8-R15) — accepted for this problem shape.
// mode 0: q/k row-normalize (+ logit_scale*log2e on q) scatter + V transpose.
// mode 1: fp32 out (M x 768).
#define GSLOT 24576   // u16 per slot: A 128*64 + B 256*64
__global__ __launch_bounds__(512, 2) void gemm_kernel(
    const u16* __restrict__ A, const u16* __restrict__ B, const float* __restrict__ bias,
    int mode, u16* __restrict__ qh, u16* __restrict__ kh, u16* __restrict__ vtp,
    float* __restrict__ outp, const float* __restrict__ lsb)
{
  __shared__ u16 L[3*GSLOT];      // 144KB
  const int tid = threadIdx.x;
  const int lane = tid & 63;
  const int w = tid >> 6;               // 0..7
  const int wm = w >> 2, wn = w & 3;    // 2M x 4N wave grid
  const int lo = lane & 15, hi = lane >> 4;

  const int bx = blockIdx.x, by = blockIdx.y;

  f32x4 zero = {0.f,0.f,0.f,0.f};
  f32x4 acc[4][4];
#pragma unroll
  for (int a=0;a<4;a++)
#pragma unroll
    for (int b=0;b<4;b++) acc[a][b] = zero;
  const u16* Ag = A + (size_t)bx*128*768;
  const u16* Bg = B + (size_t)by*256*768;
  const int srow = tid >> 3;                         // 0..63
  const int scol = (((tid & 7) ^ (srow & 7)) * 8);   // pre-swizzled source 16B-slot

  // half 0: A rows srow, srow+64 and B rows srow; half 1: B rows srow+64/128/192
#define STG(slot, kt, half) do { \
    if ((half) == 0) { \
      __builtin_amdgcn_global_load_lds((gas_u16*)(Ag + (size_t)srow*768 + (kt) + scol),      (las_u16*)(&L[(slot)*GSLOT + tid*8]),        16, 0, 0); \
      __builtin_amdgcn_global_load_lds((gas_u16*)(Ag + (size_t)(srow+64)*768 + (kt) + scol), (las_u16*)(&L[(slot)*GSLOT + 4096 + tid*8]), 16, 0, 0); \
      __builtin_amdgcn_global_load_lds((gas_u16*)(Bg + (size_t)srow*768 + (kt) + scol),      (las_u16*)(&L[(slot)*GSLOT + 8192 + tid*8]), 16, 0, 0); \
    } else { \
      __builtin_amdgcn_global_load_lds((gas_u16*)(Bg + (size_t)(srow+64)*768 + (kt) + scol),  (las_u16*)(&L[(slot)*GSLOT + 12288 + tid*8]), 16, 0, 0); \
      __builtin_amdgcn_global_load_lds((gas_u16*)(Bg + (size_t)(srow+128)*768 + (kt) + scol), (las_u16*)(&L[(slot)*GSLOT + 16384 + tid*8]), 16, 0, 0); \
      __builtin_amdgcn_global_load_lds((gas_u16*)(Bg + (size_t)(srow+192)*768 + (kt) + scol), (las_u16*)(&L[(slot)*GSLOT + 20480 + tid*8]), 16, 0, 0); \
    } \
  } while(0)

  STG(0, 0, 0);  STG(0, 0, 1);     // tile 0
  STG(1, 64, 0); STG(1, 64, 1);    // tile 1
  asm volatile("s_waitcnt vmcnt(6)" ::: "memory");   // tile 0 landed; tile 1 in flight
  __builtin_amdgcn_sched_barrier(0);
  __builtin_amdgcn_s_barrier();

  int cs = 0;                       // slot holding tile t
  for (int t = 0; t < 12; ++t) {
    const u16* LA = L + cs*GSLOT;
    const u16* LB = LA + 8192;
    int ss = cs + 2; if (ss >= 3) ss -= 3;   // slot for tile t+2
#pragma unroll
    for (int kk = 0; kk < 2; ++kk) {
      const int rsl = ((hi + 4*kk) ^ (lo & 7)) * 8;
      h8 af[4], bfr[4];
#pragma unroll
      for (int mf=0; mf<4; mf++) af[mf]  = *(const h8*)(LA + (wm*64 + mf*16 + lo)*64 + rsl);
#pragma unroll
      for (int nf=0; nf<4; nf++) bfr[nf] = *(const h8*)(LB + (wn*64 + nf*16 + lo)*64 + rsl);
      if (t < 10) STG(ss, (t+2)*64, kk);               // 3 loads per phase
      __builtin_amdgcn_s_barrier();                    // role-diversity barrier
      asm volatile("s_waitcnt lgkmcnt(0)" ::: "memory");
      __builtin_amdgcn_sched_barrier(0);
      __builtin_amdgcn_s_setprio(1);
#pragma unroll
      for (int mf=0; mf<4; mf++)
#pragma unroll
        for (int nf=0; nf<4; nf++)
          acc[mf][nf] = MFMA32(af[mf], bfr[nf], acc[mf][nf]);
      __builtin_amdgcn_s_setprio(0);
      if (kk == 1) {                                   // counted wait, once/step
        if (t < 10)       asm volatile("s_waitcnt vmcnt(6)" ::: "memory");
        else if (t == 10) asm volatile("s_waitcnt vmcnt(0)" ::: "memory");
        __builtin_amdgcn_sched_barrier(0);
      }
      __builtin_amdgcn_s_barrier();
    }
    cs += 1; if (cs >= 3) cs -= 3;
  }
#undef STG

  const int r0 = bx*128 + wm*64;
  const int j0 = by*256 + wn*64;
  if (mode == 0) {
    const int p = (j0 >= 1536) ? 2 : ((j0 >= 768) ? 1 : 0);
    float bi[4];
#pragma unroll
    for (int nf=0;nf<4;nf++) bi[nf] = bias[j0 + nf*16 + lo];
    if (p == 2) {
      // ---- V: transposed store via dead LDS; 4 per-wn tiles T[d(64)][r(128)] ----
      u16* Tt = (u16*)L + wn*8192;
#pragma unroll
      for (int mf=0; mf<4; mf++)
#pragma unroll
        for (int nf=0; nf<4; nf++) {
          int d = nf*16 + lo;
          int c = wm*16 + mf*4 + hi;          // r-chunk (r = c*4 + i), 0..31
          u16x4 pk;
#pragma unroll
          for (int i=0;i<4;i++) pk[i] = f2h(acc[mf][nf][i] + bi[nf]);
          *(u16x4*)(Tt + d*128 + ((c ^ ((d & 7) << 2)) << 2)) = pk;
        }
      __syncthreads();
      // gather 8 l-consecutive elems per task, write 16B to vt
#pragma unroll
      for (int kq=0; kq<8; kq++) {
        int idx = tid + kq*512;               // [tw][lh][d][nn], nn fastest
        int nn  = idx & 7;
        int d   = (idx >> 3) & 63;
        int lh  = (idx >> 9) & 1;
        int tw  = idx >> 10;                  // 0..3
        const u16* Ts = (const u16*)L + tw*8192;
        int hh = (by - 6)*4 + tw;
        u16x8 v8;
#pragma unroll
        for (int ll=0; ll<8; ll++) {
          int rl = (lh*8 + ll)*8 + nn;        // r_local = l_local*8 + n
          int c  = rl >> 2;
          v8[ll] = Ts[d*128 + ((c ^ ((d & 7) << 2)) << 2) + (rl & 3)];
        }
        size_t off = (((size_t)nn*12 + hh)*64 + d)*1024 + (size_t)bx*16 + lh*8;
        *(u16x8*)(vtp + off) = v8;
      }
    } else {
      // ---- q/k: fused row-normalize + scatter ----
      const int c0 = j0 - p*768;
      const int hh = c0 >> 6;
      u16* dst = (p==0) ? qh : kh;
      float qsc = 1.0f;
      if (p == 0) qsc = __expf(fminf(lsb[hh], 4.6051701859880913680f)) * 1.4426950408889634f;
#pragma unroll
      for (int mf=0; mf<4; mf++)
#pragma unroll
        for (int i=0;i<4;i++) {
          int r = r0 + mf*16 + 4*hi + i;
          int n = r & 7, l = r >> 3;
          float v[4]; float ss2 = 0.f;
#pragma unroll
          for (int nf=0;nf<4;nf++){ v[nf] = acc[mf][nf][i] + bi[nf]; ss2 += v[nf]*v[nf]; }
          ss2 += __shfl_xor(ss2, 1);
          ss2 += __shfl_xor(ss2, 2);
          ss2 += __shfl_xor(ss2, 4);
          ss2 += __shfl_xor(ss2, 8);
          float sc = qsc / fmaxf(sqrtf(ss2), 1e-12f);
          size_t base = (((size_t)n*12 + hh)*1024 + l)*64;
#pragma unroll
          for (int nf=0;nf<4;nf++)
            dst[base + nf*16 + lo] = f2h(v[nf]*sc);
        }
    }
  } else {
#pragma unroll
    for (int nf=0; nf<4; nf++) {
      int j = j0 + nf*16 + lo;
      float bi = bias[j];
#pragma unroll
      for (int mf=0; mf<4; mf++)
#pragma unroll
        for (int i=0;i<4;i++) {
          int r = r0 + mf*16 + 4*hi + i;
          outp[(size_t)r*768 + j] = acc[mf][nf][i] + bi;
        }
    }
  }
}

// ---------------- flash attention (cosine-bounded: no running max needed) ----------------
// R18: software-pipelined. Carried packed P(t) across the iter boundary (8 VGPR)
// so each inter-barrier region holds INDEPENDENT work for every pipe:
//   STAGE_WRITE(tile t+1, slot wb) [DS-write]  ||  PV(t) from lVT[vbuf] [MFMA]
//   -> lgkm(0) + s_barrier (the ONLY barrier/iter; covers all WARs: slot written
//      at iter t was last read before iter t-1's barrier)
//   -> prefetch tile t+2 [VMEM]  ->  S(t+1) from lK[wb] [MFMA]  ->  exp/pack
//      P(t+1) [VALU, overlaps next iter's PV via renaming]
// vs R14: barriers 1+1 -> 1, ds_write no longer serializes against PV, exp no
// longer serializes between QK^T and PV.
__global__ __launch_bounds__(256, 3) void flash_kernel(
    const u16* __restrict__ qh, const u16* __restrict__ kh, const u16* __restrict__ vt,
    u16* __restrict__ obuf, const float* __restrict__ hsv, const float* __restrict__ lsp)
{
  __shared__ u16 lK[2][64*64];    // [buf][k][d] swizzled 16B slots
  __shared__ u16 lVT[2][64*64];   // [buf][d][k] permuted+swizzled 8B chunks
  // XCD-locality remap: 12 heads x 8 q-tiles per XCD (3MB K+V resident in L2)
  const int lin = blockIdx.y*8 + blockIdx.x;
  const int xcd = lin & 7, g = lin >> 3;
  const int nh = xcd + 8*(g >> 3);
  const int qt = g & 7;
  const int h = nh % 12, n = nh / 12;
  const u16* Qp = qh + (size_t)nh*65536;
  const u16* Kp = kh + (size_t)nh*65536;
  const u16* Vp = vt + (size_t)nh*65536;
  const int tid = threadIdx.x, lane = tid & 63, w = tid >> 6;
  const int lo = lane & 15, hi = lane >> 4;
  const int e = lo & 7;

  // Q fragments, both q-groups: lane holds Q[q=lo(+16)][d = hi*8 + j] (+32)
  h8 qa0, qa1, qb0, qb1;
  {
    const u16* qrow = Qp + (size_t)(qt*128 + w*32 + lo)*64 + hi*8;
    qa0 = *(const h8*)qrow;          qa1 = *(const h8*)(qrow + 32);
    qb0 = *(const h8*)(qrow + 1024); qb1 = *(const h8*)(qrow + 1024 + 32);
  }
  const f32x4 zero = {0.f,0.f,0.f,0.f};
  f32x4 oA[4] = {zero,zero,zero,zero};   // O^T[d=db*16+4hi+i][q=lo]
  f32x4 oB[4] = {zero,zero,zero,zero};
  f32x4 lA4 = zero, lB4 = zero;          // row sums via ones-MFMA
  const h4 ones = {(f16)1.f,(f16)1.f,(f16)1.f,(f16)1.f};

  // fp16-overflow guard (0 for these inputs; uniform branch if ever nonzero)
  float OFF;
  {
    float b = __expf(fminf(lsp[h], 4.6051701859880913680f)) * 1.4426950408889634f;
    OFF = fmaxf(b - 15.5f, 0.f);
  }

  const int sr = tid >> 2;          // stage row (k for lK, d for lVT), 0..63
  const int c4 = tid & 3;           // stage 16B-column group
  const int sx1 = sr & 7;           // K slot16 XOR
  const int sx2 = (sr & 7) << 1;    // VT chunk8 XOR (even)

  u32x4 ka, kb, va, vb;

#define STAGE_WRITE(bf) do { \
    u16* kr = lK[bf] + sr*64; \
    *(u32x4*)(kr + (((2*c4)   ^ sx1) << 3)) = ka; \
    *(u32x4*)(kr + (((2*c4+1) ^ sx1) << 3)) = kb; \
    u16* vr = lVT[bf] + sr*64; \
    *(u32x2*)(vr + (((( 0|c4) ^ sx2) << 2))) = (u32x2){va[0], va[1]}; \
    *(u32x2*)(vr + (((( 4|c4) ^ sx2) << 2))) = (u32x2){va[2], va[3]}; \
    *(u32x2*)(vr + (((( 8|c4) ^ sx2) << 2))) = (u32x2){vb[0], vb[1]}; \
    *(u32x2*)(vr + ((((12|c4) ^ sx2) << 2))) = (u32x2){vb[2], vb[3]}; \
  } while(0)

#define PREFETCH(tt) do { \
    ka = *(const u32x4*)(Kp + (size_t)(tt)*4096 + (size_t)sr*64 + c4*16); \
    kb = *(const u32x4*)(Kp + (size_t)(tt)*4096 + (size_t)sr*64 + c4*16 + 8); \
    va = *(const u32x4*)(Vp + (size_t)sr*1024 + (size_t)(tt)*64 + c4*16); \
    vb = *(const u32x4*)(Vp + (size_t)sr*1024 + (size_t)(tt)*64 + c4*16 + 8); \
  } while(0)

#define QKT(dstA, dstB, buf) do { \
    _Pragma("unroll") \
    for (int kf=0; kf<4; kf++) { \
      const u16* krow = lK[buf] + (kf*16 + lo)*64; \
      h8 k0 = *(const h8*)(krow + (((hi  ) ^ e) << 3)); \
      h8 k1 = *(const h8*)(krow + (((hi+4) ^ e) << 3)); \
      dstA[kf] = MFMA32(k1, qa1, MFMA32(k0, qa0, zero)); \
      dstB[kf] = MFMA32(k1, qb1, MFMA32(k0, qb0, zero)); \
    } \
  } while(0)

#define EXPPACK() do { \
    if (OFF != 0.f) { \
      _Pragma("unroll") \
      for (int kf=0;kf<4;kf++) \
        _Pragma("unroll") \
        for (int i=0;i<4;i++) { sa[kf][i] -= OFF; sb[kf][i] -= OFF; } \
    } \
    _Pragma("unroll") \
    for (int kf=0;kf<4;kf++) { \
      h2 a01 = pkrtz(fast_exp2(sa[kf][0]), fast_exp2(sa[kf][1])); \
      h2 a23 = pkrtz(fast_exp2(sa[kf][2]), fast_exp2(sa[kf][3])); \
      pa[kf] = __builtin_shufflevector(a01, a23, 0, 1, 2, 3); \
      h2 b01 = pkrtz(fast_exp2(sb[kf][0]), fast_exp2(sb[kf][1])); \
      h2 b23 = pkrtz(fast_exp2(sb[kf][2]), fast_exp2(sb[kf][3])); \
      pb[kf] = __builtin_shufflevector(b01, b23, 0, 1, 2, 3); \
    } \
  } while(0)

  h4 pa[4], pb[4];
  // ---- prologue: tile 0 staged, tile 1 prefetched, P(0) computed ----
  PREFETCH(0);
  STAGE_WRITE(0);
  asm volatile("s_waitcnt lgkmcnt(0)" ::: "memory");
  __builtin_amdgcn_sched_barrier(0);
  __builtin_amdgcn_s_barrier();
  PREFETCH(1);
  {
    f32x4 sa[4], sb[4];
    QKT(sa, sb, 0);
    EXPPACK();
  }

  for (int t = 0; t < 16; ++t) {
    const int wb = (t+1) & 1;     // slot for tile t+1 (written now, K-read after barrier)
    const int vbuf = t & 1;       // V source for PV(t)
    if (t < 15) STAGE_WRITE(wb);  // DS-writes overlap the PV MFMA cluster below
    // ---- rowsums + PV(t) from lVT[vbuf] using carried pa/pb ----
#pragma unroll
    for (int kf=0;kf<4;kf++) {
      lA4 = MFMA16(ones, pa[kf], lA4);
      lB4 = MFMA16(ones, pb[kf], lB4);
    }
#pragma unroll
    for (int db=0; db<4; db++) {
      const u16* vrow = lVT[vbuf] + (db*16 + lo)*64;
      h8 v01 = *(const h8*)(vrow + ((((2*hi  ) ^ e) << 3)));
      h8 v23 = *(const h8*)(vrow + ((((2*hi+1) ^ e) << 3)));
      h4 f0 = __builtin_shufflevector(v01, v01, 0,1,2,3);
      h4 f1 = __builtin_shufflevector(v01, v01, 4,5,6,7);
      h4 f2 = __builtin_shufflevector(v23, v23, 0,1,2,3);
      h4 f3 = __builtin_shufflevector(v23, v23, 4,5,6,7);
      oA[db] = MFMA16(f0, pa[0], oA[db]);
      oB[db] = MFMA16(f0, pb[0], oB[db]);
      oA[db] = MFMA16(f1, pa[1], oA[db]);
      oB[db] = MFMA16(f1, pb[1], oB[db]);
      oA[db] = MFMA16(f2, pa[2], oA[db]);
      oB[db] = MFMA16(f2, pb[2], oB[db]);
      oA[db] = MFMA16(f3, pa[3], oA[db]);
      oB[db] = MFMA16(f3, pb[3], oB[db]);
    }
    if (t < 15) {
      asm volatile("s_waitcnt lgkmcnt(0)" ::: "memory"); // stage+PV reads drained
      __builtin_amdgcn_sched_barrier(0);
      __builtin_amdgcn_s_barrier();                      // tile t+1 visible
      if (t < 14) PREFETCH(t+2);                         // lands under S+exp+next PV
      f32x4 sa[4], sb[4];
      QKT(sa, sb, wb);                                   // S(t+1)
      EXPPACK();                                         // P(t+1) -> pa/pb
    }
  }
#undef STAGE_WRITE
#undef PREFETCH
#undef QKT
#undef EXPPACK
  // epilogue: O[q][d] = O^T / l * head_scale, store fp16 into (L,N,C)
  float hsc = hsv[h];
  float invA = hsc / lA4[0];
  float invB = hsc / lB4[0];
  int l0 = qt*128 + w*32 + lo;
  u16* dA = obuf + ((size_t)l0*8 + n)*768 + h*64;
  u16* dB = obuf + ((size_t)(l0+16)*8 + n)*768 + h*64;
#pragma unroll
  for (int db=0; db<4; db++) {
    u16x4 pk0, pk1;
#pragma unroll
    for (int i=0;i<4;i++) { pk0[i] = f2h(oA[db][i]*invA); pk1[i] = f2h(oB[db][i]*invB); }
    *(u16x4*)(dA + db*16 + hi*4) = pk0;
    *(u16x4*)(dB + db*16 + hi*4) = pk1;
  }
}

extern "C" void kernel_launch(void* const* d_in, const int* in_sizes, int n_in,
                              void* d_out, int out_size, void* d_ws, size_t ws_size,
                              hipStream_t stream)
{
  (void)in_sizes; (void)n_in; (void)out_size; (void)ws_size;
  const float* x  = (const float*)d_in[0];
  const float* w1 = (const float*)d_in[1];
  const float* b1 = (const float*)d_in[2];
  const float* ls = (const float*)d_in[3];
  const float* hs = (const float*)d_in[4];
  const float* w2 = (const float*)d_in[5];
  const float* b2 = (const float*)d_in[6];
  float* out = (float*)d_out;

  u16* x_bf  = (u16*)d_ws;            // 8192 x 768  (reused as ob after GEMM1)
  u16* w1_bf = x_bf  + 6291456;       // 2304 x 768
  u16* w2_bf = w1_bf + 1769472;       // 768 x 768
  u16* qh    = w2_bf + 589824;        // (N,H,L,D) normalized (+ls*log2e on q)
  u16* kh    = qh    + 6291456;
  u16* vt    = kh    + 6291456;       // (N,H,D,L) — written directly by gemm1
  u16* ob    = x_bf;                  // (L,N,C) fp16, aliases x_bf

  cvt3_kernel<<<8448, 256, 0, stream>>>(x, x_bf, w1, w1_bf, w2, w2_bf);
  gemm_kernel<<<dim3(64,9), 512, 0, stream>>>(x_bf, w1_bf, b1, 0, qh, kh, vt, nullptr, ls);
  flash_kernel<<<dim3(8,96), 256, 0, stream>>>(qh, kh, vt, ob, hs, ls);
  gemm_kernel<<<dim3(64,3), 512, 0, stream>>>(ob, w2_bf, b2, 1, nullptr, nullptr, nullptr, out, ls);
}